// Round 2
// baseline (480.028 us; speedup 1.0000x reference)
//
#include <hip/hip_runtime.h>
#include <stdint.h>

#define A_TOT 8400
#define B_TOT 64
#define MAX_DET 300

// ---------------- decode: DFL softmax + box + cls max/argmax ----------------
template <int HW, int W, int ABASE>
__global__ __launch_bounds__(256) void yolo_decode(
    const float* __restrict__ f, const float stride,
    float4* __restrict__ box_ws, float* __restrict__ logit_ws,
    float* __restrict__ label_ws)
{
    const int tid = blockIdx.x * 256 + threadIdx.x;   // over B*HW
    const int b = tid / HW;
    const int loc = tid - b * HW;
    const float* p = f + (size_t)b * 144 * HW + loc;

    float dist[4];
#pragma unroll
    for (int s = 0; s < 4; ++s) {
        float v[16];
        float m = -1e30f;
#pragma unroll
        for (int j = 0; j < 16; ++j) {
            v[j] = p[(s * 16 + j) * HW];
            m = fmaxf(m, v[j]);
        }
        float sum = 0.f, dot = 0.f;
#pragma unroll
        for (int j = 0; j < 16; ++j) {
            float e = __expf(v[j] - m);
            sum += e;
            dot += e * (float)j;
        }
        dist[s] = dot / sum;
    }

    float best = -1e30f;
    int bi = 0;
#pragma unroll 4
    for (int c = 0; c < 80; ++c) {
        float v = p[(64 + c) * HW];
        if (v > best) { best = v; bi = c; }   // strict > keeps first max (argmax semantics)
    }

    const int gy = loc / W;
    const int gx = loc - gy * W;
    const float ax = (float)gx + 0.5f;
    const float ay = (float)gy + 0.5f;
    const float cx = (ax + 0.5f * (dist[2] - dist[0])) * stride;
    const float cy = (ay + 0.5f * (dist[3] - dist[1])) * stride;
    const float bw = (dist[0] + dist[2]) * stride;
    const float bh = (dist[1] + dist[3]) * stride;

    const int g = b * A_TOT + ABASE + loc;
    box_ws[g] = make_float4(cx, cy, bw, bh);
    logit_ws[g] = best;
    label_ws[g] = (float)bi;
}

// ---------------- per-batch top-300 (exact, stable) + greedy NMS ----------------
__global__ __launch_bounds__(1024) void yolo_topk_nms(
    const float4* __restrict__ box_ws, const float* __restrict__ logit_ws,
    const float* __restrict__ label_ws, float* __restrict__ out)
{
    const int b = blockIdx.x;
    const int tid = threadIdx.x;
    const int lane = tid & 63;
    const int wave = tid >> 6;

    __shared__ unsigned long long keys[512];
    __shared__ float4 s_box[MAX_DET];
    __shared__ float s_conf[MAX_DET], s_label[MAX_DET];
    __shared__ float s_b1x[MAX_DET], s_b1y[MAX_DET], s_b2x[MAX_DET], s_b2y[MAX_DET], s_area[MAX_DET];
    __shared__ unsigned long long s_mask[MAX_DET][5];
    __shared__ unsigned long long s_supp[5];
    __shared__ int s_cnt;

    // ---- build ranking keys in registers: (monotone(logit) << 14) | (16383 - idx) ----
    unsigned long long kreg[9];
#pragma unroll
    for (int k = 0; k < 9; ++k) {
        const int a = tid + k * 1024;
        unsigned long long key = 0;
        if (a < A_TOT) {
            unsigned int u = __float_as_uint(logit_ws[b * A_TOT + a]);
            u ^= ((unsigned int)((int)u >> 31)) | 0x80000000u;  // monotone float->uint
            key = ((unsigned long long)u << 14) | (unsigned long long)(16383 - a);
        }
        kreg[k] = key;
    }

    // ---- binary search for the exact 300th-largest (all keys distinct) ----
    unsigned long long lo = 0, hi = (0xFFFFFFFFull << 14) | 16383ull;
    while (lo < hi) {
        const unsigned long long mid = lo + ((hi - lo) >> 1);
        int c = 0;
#pragma unroll
        for (int k = 0; k < 9; ++k) c += (kreg[k] > mid) ? 1 : 0;
#pragma unroll
        for (int off = 32; off > 0; off >>= 1) c += __shfl_down(c, off);
        if (tid == 0) s_cnt = 0;
        __syncthreads();
        if (lane == 0) atomicAdd(&s_cnt, c);
        __syncthreads();
        const int total = s_cnt;
        __syncthreads();
        if (total >= MAX_DET) lo = mid + 1; else hi = mid;
    }
    const unsigned long long V = lo;  // count(key > V) == 299, count(key >= V) == 300

    // ---- compact exactly 300 keys >= V ----
    if (tid == 0) s_cnt = 0;
    if (tid < 512) keys[tid] = 0;
    __syncthreads();
#pragma unroll
    for (int k = 0; k < 9; ++k)
        if (kreg[k] >= V) keys[atomicAdd(&s_cnt, 1)] = kreg[k];

    // ---- bitonic sort 512 descending ----
    for (int k2 = 2; k2 <= 512; k2 <<= 1) {
        for (int j = k2 >> 1; j > 0; j >>= 1) {
            __syncthreads();
            if (tid < 512) {
                const int ixj = tid ^ j;
                if (ixj > tid) {
                    unsigned long long x = keys[tid], y = keys[ixj];
                    const bool desc = ((tid & k2) == 0);
                    if (desc ? (x < y) : (x > y)) { keys[tid] = y; keys[ixj] = x; }
                }
            }
        }
    }
    __syncthreads();

    // ---- gather candidate data, precompute offset corners + area (f32, mimics ref) ----
    if (tid < MAX_DET) {
        const unsigned long long key = keys[tid];
        int a = 16383 - (int)(key & 16383ull);
        if (a >= A_TOT) a = 0;  // safety (unreachable)
        const int g = b * A_TOT + a;
        const float4 bx = box_ws[g];
        const float lg = logit_ws[g];
        const float lb = label_ws[g];
        const float cf = 1.0f / (1.0f + expf(-lg));
        s_box[tid] = bx; s_conf[tid] = cf; s_label[tid] = lb;
        const float off = lb * 10000.0f;
        const float hx = 0.5f * bx.z, hy = 0.5f * bx.w;
        const float t1x = bx.x - hx + off, t1y = bx.y - hy + off;
        const float t2x = bx.x + hx + off, t2y = bx.y + hy + off;
        s_b1x[tid] = t1x; s_b1y[tid] = t1y; s_b2x[tid] = t2x; s_b2y[tid] = t2y;
        s_area[tid] = fmaxf(t2x - t1x, 0.f) * fmaxf(t2y - t1y, 0.f);
    }
    __syncthreads();

    // ---- IOU > 0.7 bit-matrix via ballot (rows striped over 16 waves) ----
    for (int i = wave; i < MAX_DET; i += 16) {
        const float ib1x = s_b1x[i], ib1y = s_b1y[i], ib2x = s_b2x[i], ib2y = s_b2y[i];
        const float iar = s_area[i];
#pragma unroll
        for (int c = 0; c < 5; ++c) {
            const int j = c * 64 + lane;
            bool sup = false;
            if (j > i && j < MAX_DET) {
                const float xx1 = fmaxf(ib1x, s_b1x[j]);
                const float yy1 = fmaxf(ib1y, s_b1y[j]);
                const float xx2 = fminf(ib2x, s_b2x[j]);
                const float yy2 = fminf(ib2y, s_b2y[j]);
                const float iw = fmaxf(xx2 - xx1, 0.f);
                const float ih = fmaxf(yy2 - yy1, 0.f);
                const float inter = iw * ih;
                const float iou = inter / (iar + s_area[j] - inter + 1e-7f);
                sup = iou > 0.7f;
            }
            const unsigned long long m = __ballot(sup);
            if (lane == 0) s_mask[i][c] = m;
        }
    }
    if (wave == 0) {   // initial suppression = !valid
#pragma unroll
        for (int c = 0; c < 5; ++c) {
            const int j = c * 64 + lane;
            const bool inv = (j < MAX_DET) ? !(s_conf[j] > 0.001f) : true;
            const unsigned long long m = __ballot(inv);
            if (lane == 0) s_supp[c] = m;
        }
    }
    __syncthreads();

    // ---- serial greedy scan (thread 0), rows prefetched one ahead ----
    if (tid == 0) {
        unsigned long long sup0 = s_supp[0], sup1 = s_supp[1], sup2 = s_supp[2],
                           sup3 = s_supp[3], sup4 = s_supp[4];
        unsigned long long r0 = s_mask[0][0], r1 = s_mask[0][1], r2 = s_mask[0][2],
                           r3 = s_mask[0][3], r4 = s_mask[0][4];
#pragma unroll
        for (int blk = 0; blk < 5; ++blk) {
            const int jend = (blk == 4) ? (MAX_DET - 256) : 64;
            for (int j = 0; j < jend; ++j) {
                const int i = (blk << 6) + j;
                const int nx = (i + 1 < MAX_DET) ? i + 1 : i;
                const unsigned long long n0 = s_mask[nx][0], n1 = s_mask[nx][1],
                                         n2 = s_mask[nx][2], n3 = s_mask[nx][3],
                                         n4 = s_mask[nx][4];
                const unsigned long long cur =
                    (blk == 0) ? sup0 : (blk == 1) ? sup1 : (blk == 2) ? sup2
                                      : (blk == 3) ? sup3 : sup4;
                if (!((cur >> j) & 1ull)) {
                    sup0 |= r0; sup1 |= r1; sup2 |= r2; sup3 |= r3; sup4 |= r4;
                }
                r0 = n0; r1 = n1; r2 = n2; r3 = n3; r4 = n4;
            }
        }
        s_supp[0] = sup0; s_supp[1] = sup1; s_supp[2] = sup2; s_supp[3] = sup3; s_supp[4] = sup4;
    }
    __syncthreads();

    // ---- output: boxes + labels always, conf zeroed when suppressed/invalid ----
    if (tid < MAX_DET) {
        const bool supb = (s_supp[tid >> 6] >> (tid & 63)) & 1ull;
        const float4 bx = s_box[tid];
        float* o = out + ((size_t)b * MAX_DET + tid) * 6;
        o[0] = bx.x; o[1] = bx.y; o[2] = bx.z; o[3] = bx.w;
        o[4] = supb ? 0.f : s_conf[tid];
        o[5] = s_label[tid];
    }
}

extern "C" void kernel_launch(void* const* d_in, const int* in_sizes, int n_in,
                              void* d_out, int out_size, void* d_ws, size_t ws_size,
                              hipStream_t stream)
{
    const float* f0 = (const float*)d_in[0];
    const float* f1 = (const float*)d_in[1];
    const float* f2 = (const float*)d_in[2];
    float* out = (float*)d_out;

    float4* box_ws = (float4*)d_ws;                                   //  8.6 MB
    float* logit_ws = (float*)d_ws + 4ull * B_TOT * A_TOT;            //  2.15 MB
    float* label_ws = logit_ws + (size_t)B_TOT * A_TOT;               //  2.15 MB

    yolo_decode<6400, 80, 0><<<B_TOT * 6400 / 256, 256, 0, stream>>>(f0, 8.f, box_ws, logit_ws, label_ws);
    yolo_decode<1600, 40, 6400><<<B_TOT * 1600 / 256, 256, 0, stream>>>(f1, 16.f, box_ws, logit_ws, label_ws);
    yolo_decode<400, 20, 8000><<<B_TOT * 400 / 256, 256, 0, stream>>>(f2, 32.f, box_ws, logit_ws, label_ws);
    yolo_topk_nms<<<B_TOT, 1024, 0, stream>>>(box_ws, logit_ws, label_ws, out);
}